// Round 7
// baseline (241.666 us; speedup 1.0000x reference)
//
#include <hip/hip_runtime.h>
#include <hip/hip_bf16.h>

#define N_TOK 32768
#define DIM   192
#define HID   384
#define NEXP  8
#define BM    128
#define MAXT  256     // max row-tiles (BM) per expert
#define KT1   6
#define KT2   12
#define EPSV 2.220446049250313e-16f

typedef __attribute__((ext_vector_type(8))) short short8;
typedef __attribute__((ext_vector_type(4))) float f32x4;

static __device__ __forceinline__ short f2bf(float f) {
    union { __hip_bfloat16 h; short s; } u;
    u.h = __float2bfloat16(f);
    return u.s;
}

typedef const __attribute__((address_space(1))) void* gptr_t;
typedef __attribute__((address_space(3))) void* lptr_t;
#define GLOAD_LDS16(g, l) \
    __builtin_amdgcn_global_load_lds((gptr_t)(const void*)(g), (lptr_t)(void*)(l), 16, 0, 0)

// ---------------------------------------------------------------------------
// Gating, 4 lanes per token: logits = [x,emb]@w_gate; top-2; softmax;
// scatter to expert lists + inverse map; lanes q=0,1 emit bf16 x rows.
// ---------------------------------------------------------------------------
template<bool WXB>
__global__ __launch_bounds__(256) void gate_kernel(
    const float* __restrict__ x, const float* __restrict__ emb,
    const float* __restrict__ wg,
    int* __restrict__ counts, int* __restrict__ toks, float* __restrict__ gates,
    int* __restrict__ inv, short* __restrict__ xb)
{
    __shared__ float wgs[2 * DIM * NEXP];   // 12 KB
    __shared__ int cnt[NEXP];
    __shared__ int base[NEXP];
    int tid = threadIdx.x;
    for (int i = tid; i < 2 * DIM * NEXP; i += 256) wgs[i] = wg[i];
    if (tid < NEXP) cnt[tid] = 0;
    __syncthreads();

    int t = blockIdx.x * 64 + (tid >> 2);
    int q = tid & 3;
    const float* src = ((q < 2) ? x : emb) + (size_t)t * DIM + (q & 1) * 96;
    short* xrow = (WXB && q < 2) ? (xb + (size_t)t * DIM + q * 96) : nullptr;

    float acc[NEXP];
#pragma unroll
    for (int e = 0; e < NEXP; ++e) acc[e] = 0.f;

#pragma unroll 3
    for (int i = 0; i < 12; ++i) {
        float4 v0 = reinterpret_cast<const float4*>(src)[2 * i];
        float4 v1 = reinterpret_cast<const float4*>(src)[2 * i + 1];
        if (WXB && q < 2) {
            short8 s;
            s[0] = f2bf(v0.x); s[1] = f2bf(v0.y); s[2] = f2bf(v0.z); s[3] = f2bf(v0.w);
            s[4] = f2bf(v1.x); s[5] = f2bf(v1.y); s[6] = f2bf(v1.z); s[7] = f2bf(v1.w);
            *reinterpret_cast<short8*>(xrow + i * 8) = s;
        }
        const float* wr = &wgs[(q * 96 + i * 8) * NEXP];
        float vs[8] = {v0.x, v0.y, v0.z, v0.w, v1.x, v1.y, v1.z, v1.w};
#pragma unroll
        for (int u = 0; u < 8; ++u)
#pragma unroll
            for (int e = 0; e < NEXP; ++e)
                acc[e] += vs[u] * wr[u * NEXP + e];
    }

#pragma unroll
    for (int e = 0; e < NEXP; ++e) {
        acc[e] += __shfl_xor(acc[e], 1);
        acc[e] += __shfl_xor(acc[e], 2);
    }

    int i1 = 0, i2 = -1, p1 = 0, p2 = 0;
    float g1 = 0.f, g2 = 0.f;
    if (q == 0) {
        float l1 = acc[0];
#pragma unroll
        for (int e = 1; e < NEXP; ++e) { if (acc[e] > l1) { l1 = acc[e]; i1 = e; } }
        float l2 = -1e30f;
#pragma unroll
        for (int e = 0; e < NEXP; ++e) { if (e != i1 && acc[e] > l2) { l2 = acc[e]; i2 = e; } }
        g1 = 1.f / (1.f + expf(l2 - l1));
        g2 = 1.f - g1;
        p1 = atomicAdd(&cnt[i1], 1);
        p2 = atomicAdd(&cnt[i2], 1);
    }
    __syncthreads();
    if (tid < NEXP) base[tid] = atomicAdd(&counts[tid], cnt[tid]);
    __syncthreads();
    if (q == 0) {
        int o1 = base[i1] + p1;
        int o2 = base[i2] + p2;
        toks[i1 * N_TOK + o1]  = (t << 1);
        gates[i1 * N_TOK + o1] = g1;
        toks[i2 * N_TOK + o2]  = (t << 1) | 1;
        gates[i2 * N_TOK + o2] = g2;
        inv[2 * t]     = (i1 << 17) | o1;
        inv[2 * t + 1] = (i2 << 17) | o2;
    }
}

// ---------------------------------------------------------------------------
// Pack weights -> bf16 MFMA B-fragments in 12KB K-slices:
//   pb1[e][jh(2)][kt(6)][jtl(12)][lane(64)][8]   (jh halves HID: 192 cols)
//   pb2[e][kt(12)][jtl(12)][lane(64)][8]         (full DIM: 192 cols)
// One thread = one coalesced 16B fragment write.
// ---------------------------------------------------------------------------
__global__ __launch_bounds__(256) void pack_kernel(
    const float* __restrict__ w1, const float* __restrict__ w2,
    short* __restrict__ pb1, short* __restrict__ pb2)
{
    const int Q1 = NEXP * 2 * KT1 * 12 * 64;   // 73728
    const int Q2 = NEXP * KT2 * 12 * 64;       // 73728
    int gid = blockIdx.x * 256 + threadIdx.x;
    if (gid < Q1) {
        int lane = gid & 63;
        int r = gid >> 6;
        int jtl = r % 12; r /= 12;
        int kt  = r % KT1; r /= KT1;
        int jh  = r & 1; int e = r >> 1;
        int j  = jh * 192 + jtl * 16 + (lane & 15);
        int k0 = kt * 32 + (lane >> 4) * 8;
        const float* src = w1 + ((size_t)e * DIM + k0) * HID + j;
        short8 s;
#pragma unroll
        for (int t = 0; t < 8; ++t) s[t] = f2bf(src[t * HID]);
        *reinterpret_cast<short8*>(pb1 + (size_t)gid * 8) = s;
    } else if (gid < Q1 + Q2) {
        int i2 = gid - Q1;
        int lane = i2 & 63;
        int r = i2 >> 6;
        int jtl = r % 12; r /= 12;
        int kt  = r % KT2; int e = r / KT2;
        int j  = jtl * 16 + (lane & 15);
        int k0 = kt * 32 + (lane >> 4) * 8;
        const float* src = w2 + ((size_t)e * HID + k0) * DIM + j;
        short8 s;
#pragma unroll
        for (int t = 0; t < 8; ++t) s[t] = f2bf(src[t * DIM]);
        *reinterpret_cast<short8*>(pb2 + (size_t)i2 * 8) = s;
    }
}

// ---------------------------------------------------------------------------
// Pass 1: Hp[gbase+r][jh half] = gelu(x[tok(r)] @ w1[e][:,jh] + b1)
// BM=128 x BN=192, BK=32 dbuf LDS (12KB/slice) shared by 4 waves x 2 m-tiles.
// Tile-major grid: bid = tile*16 + jh*8 + e  (live blocks contiguous).
// ---------------------------------------------------------------------------
template<bool USE_XB>
__global__ __launch_bounds__(256) void h2_kernel(
    const float* __restrict__ x, const short* __restrict__ xb,
    const short* __restrict__ pb1, const float* __restrict__ b1,
    const int* __restrict__ counts, const int* __restrict__ toks,
    char* __restrict__ Hp)
{
    int bid = blockIdx.x;
    int e    = bid & 7;
    int jh   = (bid >> 3) & 1;
    int tile = bid >> 4;
    int cnt = counts[e];
    int m0 = tile * BM;
    if (m0 >= cnt) return;
    int gbase = 0;
#pragma unroll
    for (int i = 0; i < NEXP; ++i) gbase += (i < e) ? counts[i] : 0;

    __shared__ __align__(16) char wlds[2][12288];
    int tid = threadIdx.x, wave = tid >> 6, lane = tid & 63;
    int lrow = lane & 15, lgrp = lane >> 4;
    const char* wsrc = (const char*)pb1 + (size_t)(e * 2 + jh) * (KT1 * 12288);

#pragma unroll
    for (int i = 0; i < 3; ++i)
        GLOAD_LDS16(wsrc + i * 4096 + tid * 16, &wlds[0][i * 4096 + tid * 16]);

    // A fragments: 2 m-tiles x 6 kt, token-gathered
    const int* tl = toks + e * N_TOK;
    short8 a[2][KT1];
#pragma unroll
    for (int mt = 0; mt < 2; ++mt) {
        int ridx = m0 + wave * 32 + mt * 16 + lrow;
        int tok = tl[min(ridx, cnt - 1)] >> 1;
        if (USE_XB) {
            const char* xr = (const char*)xb + (size_t)tok * 384 + lgrp * 16;
#pragma unroll
            for (int kt = 0; kt < KT1; ++kt) a[mt][kt] = *(const short8*)(xr + kt * 64);
        } else {
            const char* xr = (const char*)x + (size_t)tok * 768 + lgrp * 32;
#pragma unroll
            for (int kt = 0; kt < KT1; ++kt) {
                float4 v0 = *(const float4*)(xr + kt * 128);
                float4 v1 = *(const float4*)(xr + kt * 128 + 16);
                short8 s;
                s[0] = f2bf(v0.x); s[1] = f2bf(v0.y); s[2] = f2bf(v0.z); s[3] = f2bf(v0.w);
                s[4] = f2bf(v1.x); s[5] = f2bf(v1.y); s[6] = f2bf(v1.z); s[7] = f2bf(v1.w);
                a[mt][kt] = s;
            }
        }
    }
    __syncthreads();   // stage(0) + A landed (vmcnt(0) in syncthreads)

    f32x4 acc[2][12];
#pragma unroll
    for (int mt = 0; mt < 2; ++mt)
#pragma unroll
        for (int j = 0; j < 12; ++j) acc[mt][j] = (f32x4){0.f, 0.f, 0.f, 0.f};

#pragma unroll
    for (int kt = 0; kt < KT1; ++kt) {
        if (kt + 1 < KT1) {
#pragma unroll
            for (int i = 0; i < 3; ++i)
                GLOAD_LDS16(wsrc + (kt + 1) * 12288 + i * 4096 + tid * 16,
                            &wlds[(kt + 1) & 1][i * 4096 + tid * 16]);
        }
        const char* wb = wlds[kt & 1];
#pragma unroll
        for (int jt = 0; jt < 12; ++jt) {
            short8 bb = *(const short8*)(wb + jt * 1024 + lane * 16);
            acc[0][jt] = __builtin_amdgcn_mfma_f32_16x16x32_bf16(a[0][kt], bb, acc[0][jt], 0, 0, 0);
            acc[1][jt] = __builtin_amdgcn_mfma_f32_16x16x32_bf16(a[1][kt], bb, acc[1][jt], 0, 0, 0);
        }
        if (kt + 1 < KT1) __syncthreads();   // reads done + next stage landed
    }

    const float* b1j = b1 + e * HID + jh * 192;
#pragma unroll
    for (int mt = 0; mt < 2; ++mt)
#pragma unroll
        for (int rr = 0; rr < 4; ++rr) {
            int r = m0 + wave * 32 + mt * 16 + lgrp * 4 + rr;
            if (r < cnt) {
                char* hrow = Hp + (size_t)(gbase + r) * 768 + jh * 384;
#pragma unroll
                for (int jt = 0; jt < 12; ++jt) {
                    int col = jt * 16 + lrow;
                    float h = acc[mt][jt][rr] + b1j[col];
                    float g = 0.5f * h * (1.f + erff(h * 0.70710678118654752f));
                    *(short*)(hrow + col * 2) = f2bf(g);
                }
            }
        }
}

// ---------------------------------------------------------------------------
// Pass 2 (in place): Hp row r (fp32) = gate[r] * exp(Hp_bf16[r] @ w2[e] + b2)
// BM=128 x BN=192(full DIM), BK=32, 12 phases; contiguous A reads; A ping-pong.
// Tile-major grid: bid = tile*8 + e.
// ---------------------------------------------------------------------------
__global__ __launch_bounds__(256) void y2_kernel(
    char* __restrict__ Hb,
    const short* __restrict__ pb2, const float* __restrict__ b2,
    const int* __restrict__ counts, const float* __restrict__ gates)
{
    int bid = blockIdx.x;
    int e    = bid & 7;
    int tile = bid >> 3;
    int cnt = counts[e];
    int m0 = tile * BM;
    if (m0 >= cnt) return;
    int gbase = 0;
#pragma unroll
    for (int i = 0; i < NEXP; ++i) gbase += (i < e) ? counts[i] : 0;

    __shared__ __align__(16) char wlds[2][12288];
    int tid = threadIdx.x, wave = tid >> 6, lane = tid & 63;
    int lrow = lane & 15, lgrp = lane >> 4;
    const char* wsrc = (const char*)pb2 + (size_t)e * (KT2 * 12288);

#pragma unroll
    for (int i = 0; i < 3; ++i)
        GLOAD_LDS16(wsrc + i * 4096 + tid * 16, &wlds[0][i * 4096 + tid * 16]);

    // clamped A-row base pointers (tail tiles read row cnt-1, results masked)
    int r0a = min(m0 + wave * 32 + lrow, cnt - 1);
    int r1a = min(m0 + wave * 32 + 16 + lrow, cnt - 1);
    const char* hr0 = Hb + (size_t)(gbase + r0a) * 768 + lgrp * 16;
    const char* hr1 = Hb + (size_t)(gbase + r1a) * 768 + lgrp * 16;

    short8 a[2][2];
    a[0][0] = *(const short8*)(hr0);
    a[0][1] = *(const short8*)(hr1);
    __syncthreads();   // stage(0) + A(0) landed

    f32x4 acc[2][12];
#pragma unroll
    for (int mt = 0; mt < 2; ++mt)
#pragma unroll
        for (int j = 0; j < 12; ++j) acc[mt][j] = (f32x4){0.f, 0.f, 0.f, 0.f};

#pragma unroll
    for (int kt = 0; kt < KT2; ++kt) {
        if (kt + 1 < KT2) {
#pragma unroll
            for (int i = 0; i < 3; ++i)
                GLOAD_LDS16(wsrc + (kt + 1) * 12288 + i * 4096 + tid * 16,
                            &wlds[(kt + 1) & 1][i * 4096 + tid * 16]);
            a[(kt + 1) & 1][0] = *(const short8*)(hr0 + (kt + 1) * 64);
            a[(kt + 1) & 1][1] = *(const short8*)(hr1 + (kt + 1) * 64);
        }
        const char* wb = wlds[kt & 1];
#pragma unroll
        for (int jt = 0; jt < 12; ++jt) {
            short8 bb = *(const short8*)(wb + jt * 1024 + lane * 16);
            acc[0][jt] = __builtin_amdgcn_mfma_f32_16x16x32_bf16(a[kt & 1][0], bb, acc[0][jt], 0, 0, 0);
            acc[1][jt] = __builtin_amdgcn_mfma_f32_16x16x32_bf16(a[kt & 1][1], bb, acc[1][jt], 0, 0, 0);
        }
        if (kt + 1 < KT2) __syncthreads();
    }

    const float* gl = gates + e * N_TOK;
    const float* b2e = b2 + e * DIM;
#pragma unroll
    for (int mt = 0; mt < 2; ++mt)
#pragma unroll
        for (int rr = 0; rr < 4; ++rr) {
            int r = m0 + wave * 32 + mt * 16 + lgrp * 4 + rr;
            if (r < cnt) {
                float g = gl[r];
                char* srow = Hb + (size_t)(gbase + r) * 768;
#pragma unroll
                for (int jt = 0; jt < 12; ++jt) {
                    int col = jt * 16 + lrow;
                    float y = acc[mt][jt][rr] + b2e[col];
                    *(float*)(srow + col * 4) = g * expf(y);
                }
            }
        }
}

// ---------------------------------------------------------------------------
// out[t][:] = log(slot[g1(t)][:] + slot[g2(t)][:])   (gather via inv map)
// ---------------------------------------------------------------------------
__global__ __launch_bounds__(256) void combine_kernel(
    const char* __restrict__ Hb, const int* __restrict__ inv,
    const int* __restrict__ counts, float* __restrict__ out)
{
    __shared__ int rb[NEXP];
    int tid = threadIdx.x;
    if (tid < NEXP) {
        int s = 0;
        for (int i = 0; i < tid; ++i) s += counts[i];
        rb[tid] = s;
    }
    __syncthreads();

    int gid = blockIdx.x * 256 + tid;        // over N_TOK*48
    int t = gid / 48, q = gid - t * 48;
    int v1 = inv[2 * t], v2 = inv[2 * t + 1];
    int g1 = rb[v1 >> 17] + (v1 & 0x1FFFF);
    int g2 = rb[v2 >> 17] + (v2 & 0x1FFFF);
    float4 a = *(const float4*)(Hb + (size_t)g1 * 768 + q * 16);
    float4 b = *(const float4*)(Hb + (size_t)g2 * 768 + q * 16);
    float4 o;
    float c;
    c = a.x + b.x; o.x = logf(c == 0.f ? EPSV : c);
    c = a.y + b.y; o.y = logf(c == 0.f ? EPSV : c);
    c = a.z + b.z; o.z = logf(c == 0.f ? EPSV : c);
    c = a.w + b.w; o.w = logf(c == 0.f ? EPSV : c);
    *reinterpret_cast<float4*>(out + (size_t)t * DIM + q * 4) = o;
}

// ---------------------------------------------------------------------------
extern "C" void kernel_launch(void* const* d_in, const int* in_sizes, int n_in,
                              void* d_out, int out_size, void* d_ws, size_t ws_size,
                              hipStream_t stream) {
    const float* x   = (const float*)d_in[0];
    const float* emb = (const float*)d_in[1];
    const float* wg  = (const float*)d_in[2];
    const float* w1  = (const float*)d_in[3];
    const float* b1  = (const float*)d_in[4];
    const float* w2  = (const float*)d_in[5];
    const float* b2  = (const float*)d_in[6];
    float* out = (float*)d_out;

    char* ws = (char*)d_ws;
    size_t off = 0;
    auto alloc = [&](size_t n) { size_t p = off; off = (off + n + 255) & ~(size_t)255; return p; };
    int*   counts = (int*)  (ws + alloc(256));
    int*   toks   = (int*)  (ws + alloc((size_t)NEXP * N_TOK * 4));
    float* gates  = (float*)(ws + alloc((size_t)NEXP * N_TOK * 4));
    int*   inv    = (int*)  (ws + alloc((size_t)2 * N_TOK * 4));
    short* pb1    = (short*)(ws + alloc((size_t)NEXP * DIM * HID * 2));
    short* pb2    = (short*)(ws + alloc((size_t)NEXP * HID * DIM * 2));
    char*  Hp     = (char*) (ws + alloc((size_t)2 * N_TOK * 768));   // bf16 H rows == fp32 slot rows
    size_t xoff   = alloc((size_t)N_TOK * DIM * 2);
    short* xb     = (short*)(ws + xoff);
    bool use_xb = (ws_size >= off);

    hipMemsetAsync(counts, 0, NEXP * sizeof(int), stream);

    const int QF = NEXP * 2 * KT1 * 12 * 64 + NEXP * KT2 * 12 * 64;  // 147456
    pack_kernel<<<QF / 256, 256, 0, stream>>>(w1, w2, pb1, pb2);

    if (use_xb)
        gate_kernel<true><<<N_TOK / 64, 256, 0, stream>>>(x, emb, wg, counts, toks, gates, inv, xb);
    else
        gate_kernel<false><<<N_TOK / 64, 256, 0, stream>>>(x, emb, wg, counts, toks, gates, inv, nullptr);

    if (use_xb)
        h2_kernel<true><<<MAXT * 16, 256, 0, stream>>>(x, xb, pb1, b1, counts, toks, Hp);
    else
        h2_kernel<false><<<MAXT * 16, 256, 0, stream>>>(x, nullptr, pb1, b1, counts, toks, Hp);

    y2_kernel<<<MAXT * 8, 256, 0, stream>>>(Hp, pb2, b2, counts, gates);

    combine_kernel<<<(N_TOK * 48) / 256, 256, 0, stream>>>(Hp, inv, counts, out);
}